// Round 1
// baseline (219.673 us; speedup 1.0000x reference)
//
#include <hip/hip_runtime.h>
#include <hip/hip_bf16.h>
#include <math.h>

#define B_ 32
#define T_ 2048
#define H_ 1024
#define DOUT_ 128
#define TC_ 8            // t-chunks for context partial sums
#define TCHUNK_ (T_ / TC_)  // 256

// ---------------------------------------------------------------------------
// Kernel 1: v[b,h] = dot(W_score[h,:], h_t[b,:]),  h_t[b,:] = hs[b, T-1, :]
// grid = H_ blocks of 1 wave (64 lanes). W row held in registers, reused
// across all 32 batches.
// ---------------------------------------------------------------------------
__global__ __launch_bounds__(64) void compute_v_kernel(
    const float* __restrict__ hs, const float* __restrict__ Wscore,
    float* __restrict__ v) {
  const int h = blockIdx.x;
  const int lane = threadIdx.x;  // 0..63
  float w[16];
  const float* wrow = Wscore + (size_t)h * H_;
#pragma unroll
  for (int i = 0; i < 16; ++i) w[i] = wrow[lane + 64 * i];
  for (int b = 0; b < B_; ++b) {
    const float* ht = hs + ((size_t)b * T_ + (T_ - 1)) * H_;
    float acc = 0.f;
#pragma unroll
    for (int i = 0; i < 16; ++i) acc += w[i] * ht[lane + 64 * i];
#pragma unroll
    for (int off = 32; off > 0; off >>= 1) acc += __shfl_down(acc, off);
    if (lane == 0) v[b * H_ + h] = acc;
  }
}

// ---------------------------------------------------------------------------
// Kernel 2: score[b,t] = dot(hs[b,t,:], v[b,:])
// One wave per t; 4 waves (4 t-values) per block; v[b] staged in LDS.
// grid = (T/4, B). Memory-bound: reads hs once (256 MB).
// ---------------------------------------------------------------------------
__global__ __launch_bounds__(256) void score_kernel(
    const float* __restrict__ hs, const float* __restrict__ v,
    float* __restrict__ score) {
  __shared__ float4 vs[H_ / 4];  // 4 KB
  const int b = blockIdx.y;
  const int tid = threadIdx.x;
  const float4* vb = (const float4*)(v + (size_t)b * H_);
  vs[tid] = vb[tid];
  __syncthreads();
  const int wave = tid >> 6, lane = tid & 63;
  const int t = blockIdx.x * 4 + wave;
  const float4* row = (const float4*)(hs + ((size_t)b * T_ + t) * H_);
  float acc = 0.f;
#pragma unroll
  for (int i = 0; i < 4; ++i) {
    float4 a = row[lane + 64 * i];
    float4 c = vs[lane + 64 * i];
    acc += a.x * c.x + a.y * c.y + a.z * c.z + a.w * c.w;
  }
#pragma unroll
  for (int off = 32; off > 0; off >>= 1) acc += __shfl_down(acc, off);
  if (lane == 0) score[b * T_ + t] = acc;
}

// ---------------------------------------------------------------------------
// Kernel 3: in-place softmax over T per batch. grid = B, block = 256.
// ---------------------------------------------------------------------------
__global__ __launch_bounds__(256) void softmax_kernel(float* __restrict__ score) {
  const int b = blockIdx.x;
  const int tid = threadIdx.x;
  const int wave = tid >> 6, lane = tid & 63;
  float* s = score + (size_t)b * T_;
  float vals[8];
  float m = -INFINITY;
#pragma unroll
  for (int i = 0; i < 8; ++i) {
    vals[i] = s[tid + 256 * i];
    m = fmaxf(m, vals[i]);
  }
#pragma unroll
  for (int off = 32; off > 0; off >>= 1) m = fmaxf(m, __shfl_down(m, off));
  __shared__ float wred[4];
  if (lane == 0) wred[wave] = m;
  __syncthreads();
  m = fmaxf(fmaxf(wred[0], wred[1]), fmaxf(wred[2], wred[3]));
  float sum = 0.f;
#pragma unroll
  for (int i = 0; i < 8; ++i) {
    vals[i] = expf(vals[i] - m);
    sum += vals[i];
  }
#pragma unroll
  for (int off = 32; off > 0; off >>= 1) sum += __shfl_down(sum, off);
  __syncthreads();
  __shared__ float wsum[4];
  if (lane == 0) wsum[wave] = sum;
  __syncthreads();
  const float inv = 1.f / (wsum[0] + wsum[1] + wsum[2] + wsum[3]);
#pragma unroll
  for (int i = 0; i < 8; ++i) s[tid + 256 * i] = vals[i] * inv;
}

// ---------------------------------------------------------------------------
// Kernel 4: context partials. part[b,tc,h] = sum_{t in chunk tc} hs[b,t,h]*w[b,t]
// grid = (H/256, TC, B) = 1024 blocks; block = 256 threads (thread = one h).
// Coalesced: at each t, block reads 1 KB contiguous. Reads hs once (256 MB).
// ---------------------------------------------------------------------------
__global__ __launch_bounds__(256) void context_partial_kernel(
    const float* __restrict__ hs, const float* __restrict__ w,
    float* __restrict__ part) {
  const int ht = blockIdx.x;  // h tile
  const int tc = blockIdx.y;  // t chunk
  const int b = blockIdx.z;
  const int tid = threadIdx.x;
  __shared__ float wl[TCHUNK_];
  wl[tid] = w[(size_t)b * T_ + tc * TCHUNK_ + tid];
  __syncthreads();
  const int h = ht * 256 + tid;
  const float* base = hs + ((size_t)b * T_ + (size_t)tc * TCHUNK_) * H_ + h;
  float acc = 0.f;
#pragma unroll 4
  for (int i = 0; i < TCHUNK_; ++i) acc += base[(size_t)i * H_] * wl[i];
  part[((size_t)b * TC_ + tc) * H_ + h] = acc;
}

// ---------------------------------------------------------------------------
// Kernel 5: context[b,h] = sum_tc part[b,tc,h]
// ---------------------------------------------------------------------------
__global__ __launch_bounds__(256) void context_reduce_kernel(
    const float* __restrict__ part, float* __restrict__ ctx) {
  const int idx = blockIdx.x * 256 + threadIdx.x;  // over B*H
  const int b = idx / H_, h = idx % H_;
  float acc = 0.f;
#pragma unroll
  for (int tc = 0; tc < TC_; ++tc) acc += part[((size_t)b * TC_ + tc) * H_ + h];
  ctx[idx] = acc;
}

// ---------------------------------------------------------------------------
// Kernel 6: out[b,d] = tanh( sum_j pre[b,j] * W_out[j,d] ),
// pre = concat(context[b], h_t[b]). grid = B, block = 128 (thread = one d).
// ---------------------------------------------------------------------------
__global__ __launch_bounds__(128) void out_kernel(
    const float* __restrict__ ctx, const float* __restrict__ hs,
    const float* __restrict__ Wout, float* __restrict__ out) {
  const int b = blockIdx.x;
  const int tid = threadIdx.x;  // 0..127 (= output d)
  __shared__ float pre[2 * H_];  // 8 KB
  const float* ht = hs + ((size_t)b * T_ + (T_ - 1)) * H_;
  for (int i = tid; i < H_; i += 128) {
    pre[i] = ctx[(size_t)b * H_ + i];
    pre[H_ + i] = ht[i];
  }
  __syncthreads();
  float acc = 0.f;
#pragma unroll 8
  for (int j = 0; j < 2 * H_; ++j) acc += pre[j] * Wout[(size_t)j * DOUT_ + tid];
  out[(size_t)b * DOUT_ + tid] = tanhf(acc);
}

extern "C" void kernel_launch(void* const* d_in, const int* in_sizes, int n_in,
                              void* d_out, int out_size, void* d_ws, size_t ws_size,
                              hipStream_t stream) {
  const float* hs = (const float*)d_in[0];      // (B, T, H)
  const float* Wscore = (const float*)d_in[1];  // (H, H)
  const float* Wout = (const float*)d_in[2];    // (2H, DOUT)
  float* out = (float*)d_out;                   // (B, DOUT)

  float* ws = (float*)d_ws;
  float* v = ws;                        // B*H   = 32768 floats
  float* score = ws + 32768;            // B*T   = 65536 floats (softmax in-place)
  float* ctx = ws + 32768 + 65536;      // B*H   = 32768 floats
  float* part = ws + 32768 + 65536 + 32768;  // B*TC*H = 262144 floats

  compute_v_kernel<<<dim3(H_), 64, 0, stream>>>(hs, Wscore, v);
  score_kernel<<<dim3(T_ / 4, B_), 256, 0, stream>>>(hs, v, score);
  softmax_kernel<<<dim3(B_), 256, 0, stream>>>(score);
  context_partial_kernel<<<dim3(H_ / 256, TC_, B_), 256, 0, stream>>>(hs, score, part);
  context_reduce_kernel<<<dim3(B_ * H_ / 256), 256, 0, stream>>>(part, ctx);
  out_kernel<<<dim3(B_), 128, 0, stream>>>(ctx, hs, Wout, out);
}

// Round 2
// 168.125 us; speedup vs baseline: 1.3066x; 1.3066x over previous
//
#include <hip/hip_runtime.h>
#include <hip/hip_bf16.h>
#include <math.h>

#define B_ 32
#define T_ 2048
#define H_ 1024
#define DOUT_ 128

#define KT_ 8                    // rows staged in LDS per chunk (32 KB)
#define NBLK_PER_B_ 64           // blocks per batch in fused pass
#define NT_ (T_ / NBLK_PER_B_)   // 32 t's per block
#define NCHUNK_ (NT_ / KT_)      // 4 chunks per block

// ---------------------------------------------------------------------------
// Kernel 1: v[b,h] = dot(W_score[h,:], h_t[b,:]),  h_t[b,:] = hs[b, T-1, :]
// grid = H blocks of 1 wave. W row in float4 registers, reused across b.
// W read once from HBM (4 MB); h_t (128 KB) stays L2-resident.
// ---------------------------------------------------------------------------
__global__ __launch_bounds__(64) void compute_v_kernel(
    const float* __restrict__ hs, const float* __restrict__ Wscore,
    float* __restrict__ v) {
  const int h = blockIdx.x;
  const int lane = threadIdx.x;  // 0..63
  const float4* wrow = (const float4*)(Wscore + (size_t)h * H_);
  float4 w4[4];
#pragma unroll
  for (int i = 0; i < 4; ++i) w4[i] = wrow[lane + 64 * i];
  for (int b = 0; b < B_; ++b) {
    const float4* ht = (const float4*)(hs + ((size_t)b * T_ + (T_ - 1)) * H_);
    float acc = 0.f;
#pragma unroll
    for (int i = 0; i < 4; ++i) {
      float4 a = ht[lane + 64 * i];
      acc += a.x * w4[i].x + a.y * w4[i].y + a.z * w4[i].z + a.w * w4[i].w;
    }
#pragma unroll
    for (int off = 32; off > 0; off >>= 1) acc += __shfl_down(acc, off);
    if (lane == 0) v[b * H_ + h] = acc;
  }
}

// ---------------------------------------------------------------------------
// Kernel 2 (fused): one pass over hs. Per block: 32 t-rows of batch b.
// Stage KT_=8 rows in LDS; compute 8 scores (wave-per-2-rows reduce);
// online-softmax accumulate per-thread float4 context.
// Partial (m, l, ctx[1024]) per block -> merged exactly in kernel 3.
// ---------------------------------------------------------------------------
__global__ __launch_bounds__(256) void fused_score_ctx_kernel(
    const float* __restrict__ hs, const float* __restrict__ v,
    float* __restrict__ pm, float* __restrict__ pl,
    float* __restrict__ pctx) {
  __shared__ float4 buf[KT_][256];  // 32 KB
  __shared__ float s_lds[KT_];
  const int b = blockIdx.y;
  const int blk = blockIdx.x;
  const int tid = threadIdx.x;
  const int wave = tid >> 6, lane = tid & 63;

  // v fragment for the dot phase: lane l needs v4[l + 64*i]
  const float4* vb = (const float4*)(v + (size_t)b * H_);
  float4 vreg[4];
#pragma unroll
  for (int i = 0; i < 4; ++i) vreg[i] = vb[lane + 64 * i];

  const int t0 = blk * NT_;
  const float4* hsb = (const float4*)(hs + ((size_t)b * T_ + t0) * H_);

  float m = -INFINITY, l = 0.f;
  float4 acc = {0.f, 0.f, 0.f, 0.f};

  for (int c = 0; c < NCHUNK_; ++c) {
    // stage 8 rows (each row: 256 thr x 16B = 4 KB contiguous)
#pragma unroll
    for (int r = 0; r < KT_; ++r)
      buf[r][tid] = hsb[((size_t)(c * KT_ + r)) * 256 + tid];
    __syncthreads();

    // dots: wave w computes rows 2w, 2w+1
#pragma unroll
    for (int rr = 0; rr < 2; ++rr) {
      const int r = wave * 2 + rr;
      float p = 0.f;
#pragma unroll
      for (int i = 0; i < 4; ++i) {
        float4 a = buf[r][lane + 64 * i];
        p += a.x * vreg[i].x + a.y * vreg[i].y + a.z * vreg[i].z +
             a.w * vreg[i].w;
      }
#pragma unroll
      for (int off = 32; off > 0; off >>= 1) p += __shfl_down(p, off);
      if (lane == 0) s_lds[r] = p;
    }
    __syncthreads();

    // online softmax update (redundant per-thread scalar state, consistent)
    float smax = s_lds[0];
#pragma unroll
    for (int r = 1; r < KT_; ++r) smax = fmaxf(smax, s_lds[r]);
    const float mnew = fmaxf(m, smax);
    const float scale = __expf(m - mnew);  // first iter: exp(-inf)=0
    acc.x *= scale; acc.y *= scale; acc.z *= scale; acc.w *= scale;
    l *= scale;
#pragma unroll
    for (int r = 0; r < KT_; ++r) {
      const float wr = __expf(s_lds[r] - mnew);
      l += wr;
      float4 a = buf[r][tid];
      acc.x += wr * a.x; acc.y += wr * a.y;
      acc.z += wr * a.z; acc.w += wr * a.w;
    }
    m = mnew;
    __syncthreads();  // buf reused next chunk
  }

  const int pidx = b * NBLK_PER_B_ + blk;
  if (tid == 0) { pm[pidx] = m; pl[pidx] = l; }
  ((float4*)pctx)[(size_t)pidx * 256 + tid] = acc;
}

// ---------------------------------------------------------------------------
// Kernel 3: exact merge of per-block partials.
// ctx[b,:] = sum_j exp(pm_j - M) * pctx_j / (sum_j exp(pm_j - M) * pl_j)
// grid = (4, B), block = 256; thread owns one float of a 256-float quarter.
// ---------------------------------------------------------------------------
__global__ __launch_bounds__(256) void ctx_merge_kernel(
    const float* __restrict__ pm, const float* __restrict__ pl,
    const float* __restrict__ pctx, float* __restrict__ ctx) {
  const int q = blockIdx.x;  // h quarter
  const int b = blockIdx.y;
  const int tid = threadIdx.x;
  const float* pmb = pm + b * NBLK_PER_B_;
  const float* plb = pl + b * NBLK_PER_B_;
  float M = -INFINITY;
#pragma unroll 8
  for (int j = 0; j < NBLK_PER_B_; ++j) M = fmaxf(M, pmb[j]);
  float L = 0.f;
#pragma unroll 8
  for (int j = 0; j < NBLK_PER_B_; ++j) L += plb[j] * __expf(pmb[j] - M);
  float acc = 0.f;
  const int h = q * 256 + tid;
#pragma unroll 4
  for (int j = 0; j < NBLK_PER_B_; ++j) {
    const float f = __expf(pmb[j] - M);
    acc += f * pctx[((size_t)(b * NBLK_PER_B_ + j)) * H_ + h];
  }
  ctx[(size_t)b * H_ + h] = acc / L;
}

// ---------------------------------------------------------------------------
// Kernel 4: out[b,d] = tanh( sum_j pre[b,j] * W_out[j,d] ),
// pre = concat(context[b], h_t[b]). grid = B, block = 128.
// ---------------------------------------------------------------------------
__global__ __launch_bounds__(128) void out_kernel(
    const float* __restrict__ ctx, const float* __restrict__ hs,
    const float* __restrict__ Wout, float* __restrict__ out) {
  const int b = blockIdx.x;
  const int tid = threadIdx.x;  // = output d
  __shared__ float pre[2 * H_];  // 8 KB
  const float* ht = hs + ((size_t)b * T_ + (T_ - 1)) * H_;
  for (int i = tid; i < H_; i += 128) {
    pre[i] = ctx[(size_t)b * H_ + i];
    pre[H_ + i] = ht[i];
  }
  __syncthreads();
  float acc = 0.f;
#pragma unroll 8
  for (int j = 0; j < 2 * H_; ++j) acc += pre[j] * Wout[(size_t)j * DOUT_ + tid];
  out[(size_t)b * DOUT_ + tid] = tanhf(acc);
}

extern "C" void kernel_launch(void* const* d_in, const int* in_sizes, int n_in,
                              void* d_out, int out_size, void* d_ws, size_t ws_size,
                              hipStream_t stream) {
  const float* hs = (const float*)d_in[0];      // (B, T, H)
  const float* Wscore = (const float*)d_in[1];  // (H, H)
  const float* Wout = (const float*)d_in[2];    // (2H, DOUT)
  float* out = (float*)d_out;                   // (B, DOUT)

  float* ws = (float*)d_ws;
  float* v = ws;                                   // B*H      = 32768
  float* pm = ws + 32768;                          // B*64     = 2048
  float* pl = ws + 32768 + 2048;                   // B*64     = 2048
  float* pctx = ws + 32768 + 2048 + 2048;          // 2048*H   = 2097152
  float* ctx = ws + 32768 + 2048 + 2048 + 2097152; // B*H      = 32768

  compute_v_kernel<<<dim3(H_), 64, 0, stream>>>(hs, Wscore, v);
  fused_score_ctx_kernel<<<dim3(NBLK_PER_B_, B_), 256, 0, stream>>>(hs, v, pm, pl, pctx);
  ctx_merge_kernel<<<dim3(4, B_), 256, 0, stream>>>(pm, pl, pctx, ctx);
  out_kernel<<<dim3(B_), 128, 0, stream>>>(ctx, hs, Wout, out);
}

// Round 3
// 130.284 us; speedup vs baseline: 1.6861x; 1.2905x over previous
//
#include <hip/hip_runtime.h>
#include <hip/hip_bf16.h>
#include <math.h>

#define B_ 32
#define T_ 2048
#define H_ 1024
#define DOUT_ 128

#define KT_ 8                    // rows per LDS chunk (32 KB)
#define NBLK_PER_B_ 32           // blocks per batch in fused pass
#define NT_ (T_ / NBLK_PER_B_)   // 64 t's per block
#define NCHUNK_ (NT_ / KT_)      // 8 chunks per block

#define JC_ 16                   // j-chunks for output GEMV
#define JCH_ (2 * H_ / JC_)      // 128 j per chunk

// ---------------------------------------------------------------------------
// Kernel 1: v[b,h] = dot(W_score[h,:], h_t[b,:]).
// grid = H blocks x 256 thr (4 waves); wave w handles batches 8w..8w+7.
// W row (4 KB) loaded per-wave into registers (L1-served after wave 0).
// ---------------------------------------------------------------------------
__global__ __launch_bounds__(256) void compute_v_kernel(
    const float* __restrict__ hs, const float* __restrict__ Wscore,
    float* __restrict__ v) {
  const int h = blockIdx.x;
  const int tid = threadIdx.x;
  const int wave = tid >> 6, lane = tid & 63;
  const float4* wrow = (const float4*)(Wscore + (size_t)h * H_);
  float4 w4[4];
#pragma unroll
  for (int i = 0; i < 4; ++i) w4[i] = wrow[lane + 64 * i];
#pragma unroll
  for (int bb = 0; bb < 8; ++bb) {
    const int b = wave * 8 + bb;
    const float4* ht = (const float4*)(hs + ((size_t)b * T_ + (T_ - 1)) * H_);
    float acc = 0.f;
#pragma unroll
    for (int i = 0; i < 4; ++i) {
      float4 a = ht[lane + 64 * i];
      acc += a.x * w4[i].x + a.y * w4[i].y + a.z * w4[i].z + a.w * w4[i].w;
    }
#pragma unroll
    for (int off = 32; off > 0; off >>= 1) acc += __shfl_down(acc, off);
    if (lane == 0) v[b * H_ + h] = acc;
  }
}

// ---------------------------------------------------------------------------
// Kernel 2 (fused, one pass over hs): 64 t-rows per block, 8-row chunks.
// T14 async-STAGE: next chunk loaded to registers BEFORE compute, ds_write
// after the post-compute barrier -> HBM latency hides under dot+update.
// ---------------------------------------------------------------------------
__global__ __launch_bounds__(256) void fused_score_ctx_kernel(
    const float* __restrict__ hs, const float* __restrict__ v,
    float* __restrict__ pm, float* __restrict__ pl,
    float* __restrict__ pctx) {
  __shared__ float4 buf[KT_][256];  // 32 KB
  __shared__ float s_lds[KT_];
  const int b = blockIdx.y;
  const int blk = blockIdx.x;
  const int tid = threadIdx.x;
  const int wave = tid >> 6, lane = tid & 63;

  const float4* vb = (const float4*)(v + (size_t)b * H_);
  float4 vreg[4];
#pragma unroll
  for (int i = 0; i < 4; ++i) vreg[i] = vb[lane + 64 * i];

  const int t0 = blk * NT_;
  const float4* hsb = (const float4*)(hs + ((size_t)b * T_ + t0) * H_);

  float m = -INFINITY, l = 0.f;
  float4 acc = {0.f, 0.f, 0.f, 0.f};
  float4 stg[KT_];

  // prologue: chunk 0 -> regs -> LDS
#pragma unroll
  for (int r = 0; r < KT_; ++r) stg[r] = hsb[(size_t)r * 256 + tid];
#pragma unroll
  for (int r = 0; r < KT_; ++r) buf[r][tid] = stg[r];
  __syncthreads();

  for (int c = 0; c < NCHUNK_; ++c) {
    // issue next chunk's global loads early (registers; no LDS write yet)
    if (c + 1 < NCHUNK_) {
#pragma unroll
      for (int r = 0; r < KT_; ++r)
        stg[r] = hsb[((size_t)((c + 1) * KT_ + r)) * 256 + tid];
    }

    // dot phase: wave w computes rows 2w, 2w+1
#pragma unroll
    for (int rr = 0; rr < 2; ++rr) {
      const int r = wave * 2 + rr;
      float p = 0.f;
#pragma unroll
      for (int i = 0; i < 4; ++i) {
        float4 a = buf[r][lane + 64 * i];
        p += a.x * vreg[i].x + a.y * vreg[i].y + a.z * vreg[i].z +
             a.w * vreg[i].w;
      }
#pragma unroll
      for (int off = 32; off > 0; off >>= 1) p += __shfl_down(p, off);
      if (lane == 0) s_lds[r] = p;
    }
    __syncthreads();

    // online softmax update (redundant per-thread scalar state, consistent)
    float smax = s_lds[0];
#pragma unroll
    for (int r = 1; r < KT_; ++r) smax = fmaxf(smax, s_lds[r]);
    const float mnew = fmaxf(m, smax);
    const float scale = __expf(m - mnew);  // first iter: exp(-inf)=0
    acc.x *= scale; acc.y *= scale; acc.z *= scale; acc.w *= scale;
    l *= scale;
#pragma unroll
    for (int r = 0; r < KT_; ++r) {
      const float wr = __expf(s_lds[r] - mnew);
      l += wr;
      float4 a = buf[r][tid];
      acc.x += wr * a.x; acc.y += wr * a.y;
      acc.z += wr * a.z; acc.w += wr * a.w;
    }
    m = mnew;
    __syncthreads();  // all waves done reading buf

    if (c + 1 < NCHUNK_) {
#pragma unroll
      for (int r = 0; r < KT_; ++r) buf[r][tid] = stg[r];
      __syncthreads();
    }
  }

  const int pidx = b * NBLK_PER_B_ + blk;
  if (tid == 0) { pm[pidx] = m; pl[pidx] = l; }
  ((float4*)pctx)[(size_t)pidx * 256 + tid] = acc;
}

// ---------------------------------------------------------------------------
// Kernel 3: exact merge of per-block partials.
// ctx[b,:] = sum_j exp(pm_j - M) * pctx_j / (sum_j exp(pm_j - M) * pl_j)
// ---------------------------------------------------------------------------
__global__ __launch_bounds__(256) void ctx_merge_kernel(
    const float* __restrict__ pm, const float* __restrict__ pl,
    const float* __restrict__ pctx, float* __restrict__ ctx) {
  const int q = blockIdx.x;  // h quarter
  const int b = blockIdx.y;
  const int tid = threadIdx.x;
  const float* pmb = pm + b * NBLK_PER_B_;
  const float* plb = pl + b * NBLK_PER_B_;
  float M = -INFINITY;
#pragma unroll 8
  for (int j = 0; j < NBLK_PER_B_; ++j) M = fmaxf(M, pmb[j]);
  float L = 0.f;
#pragma unroll 8
  for (int j = 0; j < NBLK_PER_B_; ++j) L += plb[j] * __expf(pmb[j] - M);
  float acc = 0.f;
  const int h = q * 256 + tid;
#pragma unroll 4
  for (int j = 0; j < NBLK_PER_B_; ++j) {
    const float f = __expf(pmb[j] - M);
    acc += f * pctx[((size_t)(b * NBLK_PER_B_ + j)) * H_ + h];
  }
  ctx[(size_t)b * H_ + h] = acc / L;
}

// ---------------------------------------------------------------------------
// Kernel 4: output GEMV partials over j-chunks.
// opart[b,jc,d] = sum_{j in chunk} pre[b,j] * Wout[j,d]
// grid = (B, JC) = 512 blocks x 128 thr.
// ---------------------------------------------------------------------------
__global__ __launch_bounds__(128) void out_partial_kernel(
    const float* __restrict__ ctx, const float* __restrict__ hs,
    const float* __restrict__ Wout, float* __restrict__ opart) {
  const int b = blockIdx.x;
  const int jc = blockIdx.y;
  const int d = threadIdx.x;  // 0..127
  __shared__ float pre[JCH_];
  const float* ht = hs + ((size_t)b * T_ + (T_ - 1)) * H_;
  {
    const int j = jc * JCH_ + d;
    pre[d] = (j < H_) ? ctx[(size_t)b * H_ + j] : ht[j - H_];
  }
  __syncthreads();
  float acc = 0.f;
#pragma unroll 8
  for (int i = 0; i < JCH_; ++i)
    acc += pre[i] * Wout[((size_t)(jc * JCH_ + i)) * DOUT_ + d];
  opart[((size_t)b * JC_ + jc) * DOUT_ + d] = acc;
}

// ---------------------------------------------------------------------------
// Kernel 5: out[b,d] = tanh( sum_jc opart[b,jc,d] )
// ---------------------------------------------------------------------------
__global__ __launch_bounds__(128) void out_reduce_kernel(
    const float* __restrict__ opart, float* __restrict__ out) {
  const int b = blockIdx.x;
  const int d = threadIdx.x;
  float acc = 0.f;
#pragma unroll
  for (int jc = 0; jc < JC_; ++jc)
    acc += opart[((size_t)b * JC_ + jc) * DOUT_ + d];
  out[(size_t)b * DOUT_ + d] = tanhf(acc);
}

extern "C" void kernel_launch(void* const* d_in, const int* in_sizes, int n_in,
                              void* d_out, int out_size, void* d_ws, size_t ws_size,
                              hipStream_t stream) {
  const float* hs = (const float*)d_in[0];      // (B, T, H)
  const float* Wscore = (const float*)d_in[1];  // (H, H)
  const float* Wout = (const float*)d_in[2];    // (2H, DOUT)
  float* out = (float*)d_out;                   // (B, DOUT)

  float* ws = (float*)d_ws;
  float* v = ws;                                // B*H            = 32768
  float* pm = v + B_ * H_;                      // B*NBLK         = 1024
  float* pl = pm + B_ * NBLK_PER_B_;            // B*NBLK         = 1024
  float* pctx = pl + B_ * NBLK_PER_B_;          // B*NBLK*H       = 1048576
  float* ctx = pctx + (size_t)B_ * NBLK_PER_B_ * H_;  // B*H      = 32768
  float* opart = ctx + B_ * H_;                 // B*JC*DOUT      = 65536

  compute_v_kernel<<<dim3(H_), 256, 0, stream>>>(hs, Wscore, v);
  fused_score_ctx_kernel<<<dim3(NBLK_PER_B_, B_), 256, 0, stream>>>(hs, v, pm, pl, pctx);
  ctx_merge_kernel<<<dim3(4, B_), 256, 0, stream>>>(pm, pl, pctx, ctx);
  out_partial_kernel<<<dim3(B_, JC_), 128, 0, stream>>>(ctx, hs, Wout, opart);
  out_reduce_kernel<<<dim3(B_), 128, 0, stream>>>(opart, out);
}

// Round 4
// 71.001 us; speedup vs baseline: 3.0940x; 1.8350x over previous
//
#include <hip/hip_runtime.h>
#include <hip/hip_bf16.h>
#include <math.h>

#define B_ 32
#define T_ 2048
#define H_ 1024
#define DOUT_ 128

#define RW_ 32                     // rows per wave (fused pass)
#define WPB_ 4                     // waves per block
#define WAVES_PER_B_ (T_ / RW_)    // 64 partials per batch
#define FBLK_ (WAVES_PER_B_ / WPB_)  // 16 blocks per batch

#define JC_ 16                     // j-chunks for output GEMV
#define JCH_ (2 * H_ / JC_)        // 128 j per chunk

// ---------------------------------------------------------------------------
// Kernel 1: v[b,h] = dot(W_score[h,:], h_t[b,:]).
// grid = H blocks x 256 thr (4 waves); wave w handles batches 8w..8w+7.
// ---------------------------------------------------------------------------
__global__ __launch_bounds__(256) void compute_v_kernel(
    const float* __restrict__ hs, const float* __restrict__ Wscore,
    float* __restrict__ v) {
  const int h = blockIdx.x;
  const int tid = threadIdx.x;
  const int wave = tid >> 6, lane = tid & 63;
  const float4* wrow = (const float4*)(Wscore + (size_t)h * H_);
  float4 w4[4];
#pragma unroll
  for (int i = 0; i < 4; ++i) w4[i] = wrow[lane + 64 * i];
#pragma unroll
  for (int bb = 0; bb < 8; ++bb) {
    const int b = wave * 8 + bb;
    const float4* ht = (const float4*)(hs + ((size_t)b * T_ + (T_ - 1)) * H_);
    float acc = 0.f;
#pragma unroll
    for (int i = 0; i < 4; ++i) {
      float4 a = ht[lane + 64 * i];
      acc += a.x * w4[i].x + a.y * w4[i].y + a.z * w4[i].z + a.w * w4[i].w;
    }
#pragma unroll
    for (int off = 32; off > 0; off >>= 1) acc += __shfl_down(acc, off);
    if (lane == 0) v[b * H_ + h] = acc;
  }
}

// ---------------------------------------------------------------------------
// Fused pass helpers: wave-private register-resident online softmax + ctx.
// Lane l owns float4 slots {l, l+64, l+128, l+192} of each 1024-float row.
// ---------------------------------------------------------------------------
__device__ __forceinline__ float dot16(const float4 (&A)[4],
                                       const float4 (&V)[4]) {
  float p = 0.f;
#pragma unroll
  for (int i = 0; i < 4; ++i)
    p += A[i].x * V[i].x + A[i].y * V[i].y + A[i].z * V[i].z + A[i].w * V[i].w;
  return p;
}

// defer-max (T13): rescale only when the new score exceeds m by >8; weights
// then bounded by e^8 — exact after the final merge renormalization.
__device__ __forceinline__ void upd_row(float p, const float4 (&R)[4],
                                        float& m, float& lsum,
                                        float4 (&acc)[4]) {
  if (p > m + 8.f) {  // wave-uniform (p is reduced), no divergence
    const float sc = __expf(m - p);
    lsum *= sc;
#pragma unroll
    for (int i = 0; i < 4; ++i) {
      acc[i].x *= sc; acc[i].y *= sc; acc[i].z *= sc; acc[i].w *= sc;
    }
    m = p;
  }
  const float w = __expf(p - m);
  lsum += w;
#pragma unroll
  for (int i = 0; i < 4; ++i) {
    acc[i].x = fmaf(w, R[i].x, acc[i].x);
    acc[i].y = fmaf(w, R[i].y, acc[i].y);
    acc[i].z = fmaf(w, R[i].z, acc[i].z);
    acc[i].w = fmaf(w, R[i].w, acc[i].w);
  }
}

#define LOADROW(dst, r)                                         \
  _Pragma("unroll") for (int i = 0; i < 4; ++i) dst[i] =        \
      rp[(size_t)(r)*256 + lane + 64 * i];

// ---------------------------------------------------------------------------
// Kernel 2 (fused, one pass over hs): wave-per-32-rows, fully in registers.
// No LDS, no barriers. Depth-4 row pipeline via 4 named buffers (static
// indexing). Partial (m, l, ctx[1024]) per wave -> merged in kernel 3.
// ---------------------------------------------------------------------------
__global__ __launch_bounds__(256) void fused_score_ctx_kernel(
    const float* __restrict__ hs, const float* __restrict__ v,
    float* __restrict__ pm, float* __restrict__ pl,
    float* __restrict__ pctx) {
  const int b = blockIdx.y;
  const int wv = blockIdx.x * WPB_ + (threadIdx.x >> 6);  // 0..63
  const int lane = threadIdx.x & 63;

  const float4* vb = (const float4*)(v + (size_t)b * H_);
  float4 vreg[4];
#pragma unroll
  for (int i = 0; i < 4; ++i) vreg[i] = vb[lane + 64 * i];

  const float4* rp =
      (const float4*)(hs + ((size_t)b * T_ + (size_t)wv * RW_) * H_);

  float4 A[4], Bv[4], C[4], D[4];
  LOADROW(A, 0);
  LOADROW(Bv, 1);

  float m = -1e30f, lsum = 0.f;
  float4 acc[4] = {{0, 0, 0, 0}, {0, 0, 0, 0}, {0, 0, 0, 0}, {0, 0, 0, 0}};

#pragma unroll
  for (int rr = 0; rr < RW_; rr += 4) {
    if (rr + 2 < RW_) { LOADROW(C, rr + 2); LOADROW(D, rr + 3); }
    float pA = dot16(A, vreg), pB = dot16(Bv, vreg);
#pragma unroll
    for (int off = 32; off > 0; off >>= 1) {  // two interleaved chains
      pA += __shfl_xor(pA, off);
      pB += __shfl_xor(pB, off);
    }
    upd_row(pA, A, m, lsum, acc);
    upd_row(pB, Bv, m, lsum, acc);
    if (rr + 4 < RW_) { LOADROW(A, rr + 4); LOADROW(Bv, rr + 5); }
    if (rr + 2 < RW_) {
      float pC = dot16(C, vreg), pD = dot16(D, vreg);
#pragma unroll
      for (int off = 32; off > 0; off >>= 1) {
        pC += __shfl_xor(pC, off);
        pD += __shfl_xor(pD, off);
      }
      upd_row(pC, C, m, lsum, acc);
      upd_row(pD, D, m, lsum, acc);
    }
  }

  const int pidx = b * WAVES_PER_B_ + wv;
  if (lane == 0) { pm[pidx] = m; pl[pidx] = lsum; }
  float4* pc = (float4*)pctx + (size_t)pidx * 256;
#pragma unroll
  for (int i = 0; i < 4; ++i) pc[lane + 64 * i] = acc[i];
}

// ---------------------------------------------------------------------------
// Kernel 3: merge partials + output GEMV partials, fused.
// grid = (B, JC) = 512 blocks x 128 thr. jc<8: merge the needed 128-float
// ctx slice from the 64 wave-partials; jc>=8: slice of h_t. Then
// opart[b,jc,d] = sum_{i} pre[i] * Wout[jc*128+i, d].
// ---------------------------------------------------------------------------
__global__ __launch_bounds__(128) void out_partial_kernel(
    const float* __restrict__ pm, const float* __restrict__ pl,
    const float* __restrict__ pctx, const float* __restrict__ hs,
    const float* __restrict__ Wout, float* __restrict__ opart) {
  const int b = blockIdx.x;
  const int jc = blockIdx.y;
  const int d = threadIdx.x;  // 0..127
  __shared__ float pre[JCH_];
  if (jc < 8) {
    const float* pmb = pm + b * WAVES_PER_B_;
    const float* plb = pl + b * WAVES_PER_B_;
    float M = -1e30f;
#pragma unroll 8
    for (int j = 0; j < WAVES_PER_B_; ++j) M = fmaxf(M, pmb[j]);
    float L = 0.f;
#pragma unroll 8
    for (int j = 0; j < WAVES_PER_B_; ++j) L += plb[j] * __expf(pmb[j] - M);
    float a = 0.f;
    const int h = jc * JCH_ + d;
#pragma unroll 4
    for (int j = 0; j < WAVES_PER_B_; ++j)
      a += __expf(pmb[j] - M) *
           pctx[((size_t)(b * WAVES_PER_B_ + j)) * H_ + h];
    pre[d] = a / L;
  } else {
    pre[d] = hs[((size_t)b * T_ + (T_ - 1)) * H_ + (jc - 8) * JCH_ + d];
  }
  __syncthreads();
  float acc = 0.f;
#pragma unroll 8
  for (int i = 0; i < JCH_; ++i)
    acc += pre[i] * Wout[((size_t)(jc * JCH_ + i)) * DOUT_ + d];
  opart[((size_t)b * JC_ + jc) * DOUT_ + d] = acc;
}

// ---------------------------------------------------------------------------
// Kernel 4: out[b,d] = tanh( sum_jc opart[b,jc,d] )
// ---------------------------------------------------------------------------
__global__ __launch_bounds__(128) void out_reduce_kernel(
    const float* __restrict__ opart, float* __restrict__ out) {
  const int b = blockIdx.x;
  const int d = threadIdx.x;
  float acc = 0.f;
#pragma unroll
  for (int jc = 0; jc < JC_; ++jc)
    acc += opart[((size_t)b * JC_ + jc) * DOUT_ + d];
  out[(size_t)b * DOUT_ + d] = tanhf(acc);
}

extern "C" void kernel_launch(void* const* d_in, const int* in_sizes, int n_in,
                              void* d_out, int out_size, void* d_ws, size_t ws_size,
                              hipStream_t stream) {
  const float* hs = (const float*)d_in[0];      // (B, T, H)
  const float* Wscore = (const float*)d_in[1];  // (H, H)
  const float* Wout = (const float*)d_in[2];    // (2H, DOUT)
  float* out = (float*)d_out;                   // (B, DOUT)

  float* ws = (float*)d_ws;
  float* v = ws;                                // B*H            = 32768
  float* pm = v + B_ * H_;                      // B*64           = 2048
  float* pl = pm + B_ * WAVES_PER_B_;           // B*64           = 2048
  float* pctx = pl + B_ * WAVES_PER_B_;         // B*64*H         = 2097152
  float* opart = pctx + (size_t)B_ * WAVES_PER_B_ * H_;  // B*JC*DOUT = 65536

  compute_v_kernel<<<dim3(H_), 256, 0, stream>>>(hs, Wscore, v);
  fused_score_ctx_kernel<<<dim3(FBLK_, B_), 256, 0, stream>>>(hs, v, pm, pl, pctx);
  out_partial_kernel<<<dim3(B_, JC_), 128, 0, stream>>>(pm, pl, pctx, hs, Wout, opart);
  out_reduce_kernel<<<dim3(B_), 128, 0, stream>>>(opart, out);
}